// Round 5
// baseline (313.092 us; speedup 1.0000x reference)
//
#include <hip/hip_runtime.h>
#include <stdint.h>

#define B_ 4
#define S_ 1001
#define SP 1008    // padded rows (63 * 16)
#define SPAD 1024  // padded t dimension (32 * 32)
#define EIN_ 256
#define EOUT_ 64
#define H_ 10
#define NCOL 640   // H*EOUT
#define NCOL3 1920
#define SCW 1016   // sc row stride in bf16; 16*SCW*2 + 16 guard + 64 wpart = 32592 B -> 5 blocks/CU

#define C1EXP 0.090168440f  // (1/16) * log2(e): exp(s/16) = exp2(s*C1EXP)

typedef short bf16x8 __attribute__((ext_vector_type(8)));
typedef short bf16x4 __attribute__((ext_vector_type(4)));
typedef float f32x4 __attribute__((ext_vector_type(4)));
typedef unsigned u32x2 __attribute__((ext_vector_type(2)));

__device__ __forceinline__ unsigned short f2bf(float f) {
  unsigned u = __float_as_uint(f);
  u += 0x7FFFu + ((u >> 16) & 1u);  // RTNE (inputs finite)
  return (unsigned short)(u >> 16);
}
__device__ __forceinline__ float bf2f(unsigned short h) {
  return __uint_as_float(((unsigned)h) << 16);
}
// pack 2 f32 -> 2 bf16 (RTNE) in one instruction; lo <- a, hi <- b
__device__ __forceinline__ unsigned cvt_pk_bf16(float a, float b) {
  unsigned r;
  asm("v_cvt_pk_bf16_f32 %0, %1, %2" : "=v"(r) : "v"(a), "v"(b));
  return r;
}

// ---- kernel 1: fp32 -> bf16 (x padded, W concat) + mask zero-padded fp32 ----
__global__ __launch_bounds__(256) void convert_kernel(
    const float* __restrict__ x, const float* __restrict__ Wq,
    const float* __restrict__ Wk, const float* __restrict__ Wv,
    const float* __restrict__ mask, unsigned short* __restrict__ xbf,
    unsigned short* __restrict__ wbf, float* __restrict__ mpad) {
  int i = blockIdx.x * 256 + threadIdx.x;
  const int N1 = B_ * SP * EIN_;   // 1,032,192
  const int N2 = NCOL3 * EIN_;     // 491,520
  const int N3 = SP * SPAD;        // 1,032,192
  if (i < N1) {
    int b = i / (SP * EIN_);
    int rem = i % (SP * EIN_);
    int row = rem / EIN_;
    int e = rem % EIN_;
    float v = (row < S_) ? x[((size_t)(b * S_ + row)) * EIN_ + e] : 0.0f;
    xbf[i] = f2bf(v);
  } else if (i < N1 + N2) {
    int j = i - N1;
    int col = j / EIN_;
    int e = j % EIN_;
    int mat = col / NCOL;
    int hcol = col % NCOL;
    const float* W = (mat == 0) ? Wq : (mat == 1) ? Wk : Wv;
    wbf[j] = f2bf(W[(size_t)hcol * EIN_ + e]);
  } else if (i < N1 + N2 + N3) {
    int j = i - N1 - N2;
    int row = j >> 10;
    int col = j & 1023;
    mpad[j] = (row < S_ && col < S_) ? mask[(size_t)row * S_ + col] : 0.0f;
  }
}

// ---------------- kernel 2: projection GEMM (MFMA bf16), 6-way N split ------
// W-fragment loads batched (4+4 in flight) instead of serial load->MFMA chain.
__global__ __launch_bounds__(256, 4) void proj_kernel(
    const unsigned short* __restrict__ xbf, const unsigned short* __restrict__ wbf,
    const float* __restrict__ bq, const float* __restrict__ bk,
    const float* __restrict__ bv, unsigned short* __restrict__ qbf,
    unsigned short* __restrict__ kbf, unsigned short* __restrict__ vrow) {
  int tid = threadIdx.x;
  int wv_ = tid >> 6;
  int l = tid & 63;
  int qd = l >> 4;
  int c = l & 15;
  int bid = blockIdx.x;
  int g = bid % 6;
  int t2 = bid / 6;
  int b = t2 / 63;
  int tile = t2 % 63;
  int s0 = tile * 16;

  bf16x8 af[8];
  const unsigned short* xrowp = xbf + (size_t)(b * SP + s0 + c) * EIN_;
#pragma unroll
  for (int ks = 0; ks < 8; ++ks)
    af[ks] = *(const bf16x8*)(xrowp + ks * 32 + qd * 8);

  for (int nt = g * 20 + wv_; nt < g * 20 + 20; nt += 4) {
    int col0 = nt * 16;
    f32x4 acc = {0.f, 0.f, 0.f, 0.f};
    const unsigned short* wrow = wbf + (size_t)(col0 + c) * EIN_;
    bf16x8 bf0[4], bf1[4];
#pragma unroll
    for (int j = 0; j < 4; ++j) bf0[j] = *(const bf16x8*)(wrow + j * 32 + qd * 8);
#pragma unroll
    for (int j = 0; j < 4; ++j) bf1[j] = *(const bf16x8*)(wrow + (4 + j) * 32 + qd * 8);
#pragma unroll
    for (int j = 0; j < 4; ++j)
      acc = __builtin_amdgcn_mfma_f32_16x16x32_bf16(af[j], bf0[j], acc, 0, 0, 0);
#pragma unroll
    for (int j = 0; j < 4; ++j)
      acc = __builtin_amdgcn_mfma_f32_16x16x32_bf16(af[4 + j], bf1[j], acc, 0, 0, 0);
    int col = col0 + c;
    int mat = col / NCOL;
    int hcol = col % NCOL;
    int hh = hcol >> 6;
    int o = hcol & 63;
    const float* bias = (mat == 0) ? bq : (mat == 1) ? bk : bv;
    float bb = bias[hcol];
    unsigned short* dst = (mat == 0) ? qbf : (mat == 1) ? kbf : vrow;
    size_t base = ((size_t)(b * H_ + hh)) * SPAD * EOUT_ + o;
#pragma unroll
    for (int i = 0; i < 4; ++i) {
      int srow = s0 + qd * 4 + i;
      float v = (srow < S_) ? (acc[i] + bb) : 0.0f;  // zero pad rows
      dst[base + (size_t)srow * EOUT_] = f2bf(v);
    }
  }
}

// ---------------- kernel 3: v [t][o] -> vT [o][t] ----------------
__global__ __launch_bounds__(256) void transpose_v(
    const unsigned short* __restrict__ vrow, unsigned short* __restrict__ vT) {
  __shared__ unsigned short tl[64 * 65];
  int bid = blockIdx.x;
  int bh = bid >> 4;
  int t0 = (bid & 15) * 64;
  int tid = threadIdx.x;
#pragma unroll
  for (int i = 0; i < 16; ++i) {
    int idx = i * 256 + tid;
    int o = idx & 63;
    int t_l = idx >> 6;
    int row = t0 + t_l;
    tl[o * 65 + t_l] =
        (row < SP) ? vrow[((size_t)bh * SPAD + row) * EOUT_ + o] : (unsigned short)0;
  }
  __syncthreads();
#pragma unroll
  for (int i = 0; i < 16; ++i) {
    int idx = i * 256 + tid;
    int t_l = idx & 63;
    int o = idx >> 6;
    vT[((size_t)bh * EOUT_ + o) * SPAD + t0 + t_l] = tl[o * 65 + t_l];
  }
}

// ---------------- kernel 4: attention (concat out + rs export) ----------------
// MLP-focused build: depth-3 ring prefetch of K+mask in phase A (~9 loads in
// flight; ring WAR dependence keeps issue 3 tiles ahead of use), double-buffered
// V prefetch in phase D. LDS = 32592 B -> 5 blocks/CU (wpart via ds atomicAdd).
// Final concat stores are nontemporal so 10 MB of output doesn't evict L2's
// K/V/mask working set. 2-D XCD partition kept (xr=tile half, xc=batch).
__global__ __launch_bounds__(256, 5) void attn_kernel(
    const unsigned short* __restrict__ qbf, const unsigned short* __restrict__ kbf,
    const unsigned short* __restrict__ vT, const float* __restrict__ mpad,
    float* __restrict__ rsbuf, float* __restrict__ out) {
  __shared__ unsigned short sc[16 * SCW + 8];  // +8 bf16 = 16 B zero guard
  __shared__ float wpart[16];                  // per-q-row sumsq (atomic)

  int tid = threadIdx.x;
  int wv_ = tid >> 6;
  int l = tid & 63;
  int qd = l >> 4;
  int c = l & 15;

  int bid0 = blockIdx.x;
  // grid 2560 = 8 XCD * 320. XCD (xr,xc): xr = tile half, xc = batch b.
  // Within an XCD, slots run h-fastest so same-tile blocks share mask lines.
  int x_ = bid0 & 7;
  int s_ = bid0 >> 3;        // 0..319
  int xr = x_ >> 2;
  int ti = s_ / 10;          // 0..31
  int h = s_ - ti * 10;      // 0..9
  int tile = xr * 32 + ti;
  if (tile >= 63) return;    // 40 pad blocks (uniform per block, before barriers)
  int b = x_ & 3;
  int s0 = tile * 16;

  size_t bh = (size_t)(b * H_ + h);
  const unsigned short* qb = qbf + bh * SPAD * EOUT_;
  const unsigned short* kb = kbf + bh * SPAD * EOUT_;
  const unsigned short* vb = vT + bh * EOUT_ * SPAD;
  float* concat = out;  // [B,S,640]

  // Q fragment (B-operand of swapped MFMA): lane holds Q[s0 + (l&15)][...]
  bf16x8 aq0 = *(const bf16x8*)(qb + (size_t)(s0 + c) * EOUT_ + qd * 8);
  bf16x8 aq1 = *(const bf16x8*)(qb + (size_t)(s0 + c) * EOUT_ + 32 + qd * 8);
  // per-lane mask row pointer (q-row = l&15), loop-invariant
  const float* mrow = mpad + (size_t)(s0 + c) * SPAD + qd * 4;
  const size_t koff = (size_t)c * EOUT_ + qd * 8;

  // ---- ring preload: slots 0..2 = tiles wv*16 + {0,1,2} (tile <= 50, valid) --
  bf16x8 kr0[3], kr1[3];
  f32x4 mr[3];
#pragma unroll
  for (int p = 0; p < 3; ++p) {
    int t0 = (wv_ * 16 + p) * 16;
    const unsigned short* kr = kb + (size_t)t0 * EOUT_ + koff;
    kr0[p] = *(const bf16x8*)kr;
    kr1[p] = *(const bf16x8*)(kr + 32);
    mr[p] = *(const f32x4*)(mrow + t0);
  }

  if (tid < 16) wpart[tid] = 0.0f;
  __syncthreads();  // barrier 1 (start; global loads stay in flight)

  // ---- phase A: mfma(K,Q) -> in-register exp*mask, sumsq, pack; ring depth-3 --
  float nacc = 0.0f;
#pragma unroll
  for (int jj = 0; jj < 16; ++jj) {
    const int sl = jj % 3;  // fully unrolled -> static index
    int tw = wv_ * 16 + jj;
    if (wv_ < 3 || jj < 15) {  // tile 63 (wv=3, jj=15) is pad
      int t0 = tw * 16;
      f32x4 acc = {0.f, 0.f, 0.f, 0.f};
      acc = __builtin_amdgcn_mfma_f32_16x16x32_bf16(kr0[sl], aq0, acc, 0, 0, 0);
      acc = __builtin_amdgcn_mfma_f32_16x16x32_bf16(kr1[sl], aq1, acc, 0, 0, 0);
      float l0 = exp2f(acc[0] * C1EXP) * mr[sl][0];
      float l1 = exp2f(acc[1] * C1EXP) * mr[sl][1];
      float l2 = exp2f(acc[2] * C1EXP) * mr[sl][2];
      float l3 = exp2f(acc[3] * C1EXP) * mr[sl][3];
      nacc += l0 * l0 + l1 * l1 + l2 * l2 + l3 * l3;
      u32x2 pp;
      pp[0] = cvt_pk_bf16(l0, l1);
      pp[1] = cvt_pk_bf16(l2, l3);
      *(u32x2*)&sc[c * SCW + t0 + qd * 4] = pp;  // row=q, col=t
    }
    if (jj < 13) {  // prefetch tile tw+3 into the slot just consumed
      int twp = tw + 3;
      if (wv_ < 3 || twp < 63) {
        int t0p = twp * 16;
        const unsigned short* kr = kb + (size_t)t0p * EOUT_ + koff;
        kr0[sl] = *(const bf16x8*)kr;
        kr1[sl] = *(const bf16x8*)(kr + 32);
        mr[sl] = *(const f32x4*)(mrow + t0p);
      }
    }
  }
  // reduce sumsq across the 4 qd-groups sharing a q-row, then combine waves
  nacc += __shfl_xor(nacc, 16);
  nacc += __shfl_xor(nacc, 32);
  if (l < 16) atomicAdd(&wpart[l], nacc);

  // cols 1008..1015 of each row + the 16 B guard after row 15 must be finite
  // (phase D k-tail reads them against zero B fragments): zero them.
  if (tid < 128) sc[(tid >> 3) * SCW + 1008 + (tid & 7)] = 0;
  if (tid < 8) sc[16 * SCW + tid] = 0;
  __syncthreads();  // barrier 2

  if (tid < 16)
    rsbuf[((size_t)bh * 63 + tile) * 16 + tid] =
        1.0f / fmaxf(sqrtf(wpart[tid]), 1e-12f);

  // ---- phase D: out = (loc V) * rs[row]; double-buffered V prefetch ----
  // kstep 31 reads A cols 992..1023: 992..1007 real, 1008..1015 zeroed,
  // 1016..1023 wrap to next row / guard (finite) -- all multiplied by
  // vT[t>=1008] == 0, so contribution is exactly 0.
  f32x4 oacc = {0.f, 0.f, 0.f, 0.f};
  const unsigned short* vptr = vb + (size_t)(wv_ * 16 + c) * SPAD + qd * 8;
  const unsigned short* scrow = &sc[c * SCW + qd * 8];
  bf16x8 vA[4], vB[4];
#pragma unroll
  for (int j = 0; j < 4; ++j) vA[j] = *(const bf16x8*)(vptr + j * 32);
#pragma unroll
  for (int gp = 0; gp < 4; ++gp) {
    // prefetch odd group (2gp+1) into vB
#pragma unroll
    for (int j = 0; j < 4; ++j)
      vB[j] = *(const bf16x8*)(vptr + ((2 * gp + 1) * 4 + j) * 32);
#pragma unroll
    for (int j = 0; j < 4; ++j) {
      bf16x8 a = *(const bf16x8*)(scrow + ((2 * gp) * 4 + j) * 32);
      oacc = __builtin_amdgcn_mfma_f32_16x16x32_bf16(a, vA[j], oacc, 0, 0, 0);
    }
    if (gp < 3) {  // prefetch next even group (2gp+2) into vA
#pragma unroll
      for (int j = 0; j < 4; ++j)
        vA[j] = *(const bf16x8*)(vptr + ((2 * gp + 2) * 4 + j) * 32);
    }
#pragma unroll
    for (int j = 0; j < 4; ++j) {
      bf16x8 a = *(const bf16x8*)(scrow + ((2 * gp + 1) * 4 + j) * 32);
      oacc = __builtin_amdgcn_mfma_f32_16x16x32_bf16(a, vB[j], oacc, 0, 0, 0);
    }
  }
#pragma unroll
  for (int i = 0; i < 4; ++i) {
    int row = qd * 4 + i;
    int srow = s0 + row;
    if (srow < S_) {
      float rsv = 1.0f / fmaxf(sqrtf(wpart[row]), 1e-12f);
      __builtin_nontemporal_store(
          oacc[i] * rsv,
          &concat[((size_t)(b * S_) + srow) * NCOL + h * EOUT_ + wv_ * 16 + c]);
    }
  }
}

// ---- kernel 5: wsum[b,s,t] = mask[s,t] * sum_h rs_h[s] * exp(score_h[s,t]) ----
// K loads batched 8-wide per head; Q fragments double-buffered across heads.
// Output stores nontemporal (16 MB, never re-read).
__global__ __launch_bounds__(256, 4) void wsum_kernel(
    const unsigned short* __restrict__ qbf, const unsigned short* __restrict__ kbf,
    const float* __restrict__ rsbuf, const float* __restrict__ mask,
    float* __restrict__ out) {
  __shared__ float wrs[H_ * 16];
  int tid = threadIdx.x;
  int wv_ = tid >> 6;
  int l = tid & 63;
  int qd = l >> 4;
  int c = l & 15;
  int bid0 = blockIdx.x;
  // XCD swizzle: 1008 = 8 * 126; co-locate same-tile blocks per XCD.
  int bid = (bid0 & 7) * 126 + (bid0 >> 3);
  int tchunk = bid & 3;
  int rem = bid >> 2;
  int tile = rem % 63;
  int b = rem / 63;
  int s0 = tile * 16;
  int tb = tchunk * 256 + wv_ * 64;

  if (tid < H_ * 16) {
    int hh = tid >> 4, row = tid & 15;
    wrs[tid] = rsbuf[((size_t)(b * H_ + hh) * 63 + tile) * 16 + row];
  }
  __syncthreads();

  float wacc[16];
#pragma unroll
  for (int i = 0; i < 16; ++i) wacc[i] = 0.0f;

  const size_t qoff = (size_t)(s0 + c) * EOUT_ + qd * 8;
  bf16x8 qA0, qA1, qB0, qB1;
  {
    const unsigned short* qb = qbf + (size_t)(b * H_) * SPAD * EOUT_;
    qA0 = *(const bf16x8*)(qb + qoff);
    qA1 = *(const bf16x8*)(qb + qoff + 32);
  }
#pragma unroll
  for (int h = 0; h < H_; ++h) {
    size_t bh = (size_t)(b * H_ + h);
    const unsigned short* kb = kbf + bh * SPAD * EOUT_;
    // batch all 8 K loads for this head
    bf16x8 kf0[4], kf1[4];
#pragma unroll
    for (int st = 0; st < 4; ++st) {
      const unsigned short* krow = kb + (size_t)(tb + st * 16 + c) * EOUT_ + qd * 8;
      kf0[st] = *(const bf16x8*)krow;
      kf1[st] = *(const bf16x8*)(krow + 32);
    }
    // prefetch next head's Q fragments
    if (h + 1 < H_) {
      const unsigned short* qb = qbf + (bh + 1) * SPAD * EOUT_;
      if (h & 1) {
        qA0 = *(const bf16x8*)(qb + qoff);
        qA1 = *(const bf16x8*)(qb + qoff + 32);
      } else {
        qB0 = *(const bf16x8*)(qb + qoff);
        qB1 = *(const bf16x8*)(qb + qoff + 32);
      }
    }
    bf16x8 q0 = (h & 1) ? qB0 : qA0;
    bf16x8 q1 = (h & 1) ? qB1 : qA1;
    f32x4 acc[4];
#pragma unroll
    for (int st = 0; st < 4; ++st) {
      f32x4 a = {0.f, 0.f, 0.f, 0.f};
      a = __builtin_amdgcn_mfma_f32_16x16x32_bf16(q0, kf0[st], a, 0, 0, 0);
      a = __builtin_amdgcn_mfma_f32_16x16x32_bf16(q1, kf1[st], a, 0, 0, 0);
      acc[st] = a;
    }
#pragma unroll
    for (int st = 0; st < 4; ++st)
#pragma unroll
      for (int i = 0; i < 4; ++i)
        wacc[st * 4 + i] += wrs[h * 16 + qd * 4 + i] * exp2f(acc[st][i] * C1EXP);
  }

  float* wsum = out + (size_t)B_ * S_ * NCOL;
#pragma unroll
  for (int st = 0; st < 4; ++st) {
    int t = tb + st * 16 + c;
#pragma unroll
    for (int i = 0; i < 4; ++i) {
      int srow = s0 + qd * 4 + i;
      if (srow < S_ && t < S_)
        __builtin_nontemporal_store(
            wacc[st * 4 + i] * mask[(size_t)srow * S_ + t],
            &wsum[((size_t)b * S_ + srow) * S_ + t]);
    }
  }
}

extern "C" void kernel_launch(void* const* d_in, const int* in_sizes, int n_in,
                              void* d_out, int out_size, void* d_ws, size_t ws_size,
                              hipStream_t stream) {
  const float* x = (const float*)d_in[0];
  const float* mask = (const float*)d_in[1];
  const float* Wq = (const float*)d_in[2];
  const float* bq = (const float*)d_in[3];
  const float* Wk = (const float*)d_in[4];
  const float* bk = (const float*)d_in[5];
  const float* Wv = (const float*)d_in[6];
  const float* bv = (const float*)d_in[7];
  float* out = (float*)d_out;

  char* ws = (char*)d_ws;
  const size_t NEED = 28308992;
  if (ws_size < NEED) return;  // fail cleanly rather than OOB
  unsigned short* xbf  = (unsigned short*)ws;              // 2,064,384 B
  unsigned short* wbf  = (unsigned short*)(ws + 2064384);  //   983,040 B
  unsigned short* qbf  = (unsigned short*)(ws + 3047424);  // 5,242,880 B
  unsigned short* kbf  = (unsigned short*)(ws + 8290304);  // 5,242,880 B
  unsigned short* vrow = (unsigned short*)(ws + 13533184); // 5,242,880 B
  unsigned short* vT   = (unsigned short*)(ws + 18776064); // 5,242,880 B
  float*          mpad = (float*)(ws + 24018944);          // 4,128,768 B
  float*          rsbuf = (float*)(ws + 28147712);         //   161,280 B

  convert_kernel<<<9984, 256, 0, stream>>>(x, Wq, Wk, Wv, mask, xbf, wbf, mpad);
  proj_kernel<<<1512, 256, 0, stream>>>(xbf, wbf, bq, bk, bv, qbf, kbf, vrow);
  transpose_v<<<640, 256, 0, stream>>>(vrow, vT);
  attn_kernel<<<2560, 256, 0, stream>>>(qbf, kbf, vT, mpad, rsbuf, out);
  wsum_kernel<<<1008, 256, 0, stream>>>(qbf, kbf, rsbuf, mask, out);
}